// Round 2
// baseline (42.278 us; speedup 1.0000x reference)
//
#include <hip/hip_runtime.h>

#define MARGIN1 0.5f
#define MARGIN2 1.0f

// One wave (64 lanes) per 2 CONSECUTIVE groups of 3 rows (12 KB contiguous).
// Lane l covers floats [4l,4l+4) and [256+4l,256+4l+4) of each 512-float row
// -> 6 coalesced float4 loads per group. Row sums via 6-step 64-lane butterfly
// (3 independent chains interleave; they also hide the next group's loads).
// Block partial goes straight to d_out via one device-scope atomicAdd
// (d_out zeroed each call by a memset node captured in the graph).
__global__ __launch_bounds__(256, 8) void soso_main_kernel(
    const int* __restrict__ lab,
    const float* __restrict__ emb,
    const float* __restrict__ proto,
    float* __restrict__ out,
    int ngroups,
    float inv_count)
{
    const int lane  = threadIdx.x & 63;
    const int wid   = threadIdx.x >> 6;           // 0..3
    const int gwave = blockIdx.x * 4 + wid;       // global wave id
    const int g0    = gwave * 2;                  // first of 2 consecutive groups

    // proto fragment in registers, reused for all rows
    const float4 p0 = *reinterpret_cast<const float4*>(proto + 4 * lane);
    const float4 p1 = *reinterpret_cast<const float4*>(proto + 256 + 4 * lane);

    float acc = 0.0f;

#pragma unroll
    for (int gg = 0; gg < 2; ++gg) {
        const int g = g0 + gg;
        if (g < ngroups) {
            const float* base = emb + (size_t)g * 1536u;   // 3 rows * 512
            float ds[3];
#pragma unroll
            for (int r = 0; r < 3; ++r) {
                const float* row = base + r * 512;
                const float4 e0 = *reinterpret_cast<const float4*>(row + 4 * lane);
                const float4 e1 = *reinterpret_cast<const float4*>(row + 256 + 4 * lane);
                float s = 0.0f, t;
                t = p0.x - e0.x; s = fmaf(t, t, s);
                t = p0.y - e0.y; s = fmaf(t, t, s);
                t = p0.z - e0.z; s = fmaf(t, t, s);
                t = p0.w - e0.w; s = fmaf(t, t, s);
                t = p1.x - e1.x; s = fmaf(t, t, s);
                t = p1.y - e1.y; s = fmaf(t, t, s);
                t = p1.z - e1.z; s = fmaf(t, t, s);
                t = p1.w - e1.w; s = fmaf(t, t, s);
#pragma unroll
                for (int off = 32; off > 0; off >>= 1)
                    s += __shfl_xor(s, off, 64);
                ds[r] = s;
            }
            // wave-uniform label reads; branchless map label->distance
            const int l0 = lab[3 * g + 0];
            const int l1 = lab[3 * g + 1];
            const float d1 = (l0 == 0) ? ds[0] : (l1 == 0) ? ds[1] : ds[2];
            const float d2 = (l0 == 1) ? ds[0] : (l1 == 1) ? ds[1] : ds[2];
            const float d3 = (l0 == 2) ? ds[0] : (l1 == 2) ? ds[1] : ds[2];

            acc += fmaxf(d1 - d2 + MARGIN1, 0.0f)
                 + fmaxf(d2 - d3 + MARGIN1, 0.0f)
                 + fmaxf(d1 - d3 + MARGIN2, 0.0f);
        }
    }

    // acc is wave-uniform; combine the block's 4 waves, one atomic per block.
    __shared__ float smem[4];
    if (lane == 0) smem[wid] = acc;
    __syncthreads();
    if (threadIdx.x == 0) {
        const float blockSum = (smem[0] + smem[1] + smem[2] + smem[3]) * inv_count;
        atomicAdd(out, blockSum);   // device-scope, coherent across XCDs
    }
}

extern "C" void kernel_launch(void* const* d_in, const int* in_sizes, int n_in,
                              void* d_out, int out_size, void* d_ws, size_t ws_size,
                              hipStream_t stream)
{
    const int*   lab   = (const int*)d_in[0];    // true_label [B] int32
    const float* emb   = (const float*)d_in[1];  // embedding  [B,512] f32
    const float* proto = (const float*)d_in[2];  // proto      [512]   f32
    float* out = (float*)d_out;

    const int B = in_sizes[0];
    const int ngroups = B / 3;                         // 16384
    const int waves   = (ngroups + 1) / 2;             // 2 groups per wave
    const int blocks  = (waves + 3) / 4;               // 4 waves per block -> 2048

    // zero the accumulator every call (captured as a graph memset node)
    hipMemsetAsync(out, 0, sizeof(float), stream);

    soso_main_kernel<<<blocks, 256, 0, stream>>>(lab, emb, proto, out,
                                                 ngroups, 1.0f / (float)ngroups);
}